// Round 1
// baseline (1631.862 us; speedup 1.0000x reference)
//
#include <hip/hip_runtime.h>
#include <hip/hip_bf16.h>
#include <math.h>

#define NN 50000
#define NE 800000
#define F_IN 11
#define HID 128
#define NEG_SLOPE 0.2f

__device__ __forceinline__ unsigned fmap(float f) {
  unsigned u = __float_as_uint(f);
  return (u & 0x80000000u) ? ~u : (u | 0x80000000u);
}
__device__ __forceinline__ float funmap(unsigned u) {
  return (u & 0x80000000u) ? __uint_as_float(u ^ 0x80000000u) : __uint_as_float(~u);
}
__device__ __forceinline__ float lrelu(float x) { return x > 0.f ? x : NEG_SLOPE * x; }
__device__ __forceinline__ float elu1(float x) { return x > 0.f ? x : expm1f(x); }

// ---------- CSR build ----------
__global__ void k_deg(const int* __restrict__ ei, int* __restrict__ deg) {
  int e = blockIdx.x * blockDim.x + threadIdx.x;
  if (e < NE) atomicAdd(&deg[ei[NE + e]], 1);
}

__global__ void k_scan(const int* __restrict__ deg, int* __restrict__ row_ptr,
                       int* __restrict__ cursor) {
  const int T = 1024;
  const int CH = (NN + T - 1) / T;  // 49
  __shared__ int ssum[T];
  int t = threadIdx.x;
  int base = t * CH;
  int s = 0;
  for (int i = 0; i < CH; i++) {
    int idx = base + i;
    if (idx < NN) s += deg[idx];
  }
  ssum[t] = s;
  __syncthreads();
  for (int off = 1; off < T; off <<= 1) {
    int v = (t >= off) ? ssum[t - off] : 0;
    __syncthreads();
    ssum[t] += v;
    __syncthreads();
  }
  int run = ssum[t] - s;  // exclusive prefix
  for (int i = 0; i < CH; i++) {
    int idx = base + i;
    if (idx < NN) {
      row_ptr[idx] = run;
      cursor[idx] = run;
      run += deg[idx];
    }
  }
  if (t == 0) row_ptr[NN] = ssum[T - 1];
}

__global__ void k_scatter(const int* __restrict__ ei, int* __restrict__ cursor,
                          int* __restrict__ csr_src) {
  int e = blockIdx.x * blockDim.x + threadIdx.x;
  if (e < NE) {
    int d = ei[NE + e];
    int pos = atomicAdd(&cursor[d], 1);
    csr_src[pos] = ei[e];
  }
}

// ---------- layer-1 GEMM (K=11) ----------
__global__ void k_gemm_fin(const float* __restrict__ X, const float* __restrict__ W,
                           float* __restrict__ O) {
  int n = blockIdx.x;
  int j = blockIdx.y * 256 + threadIdx.x;
  float acc = 0.f;
#pragma unroll
  for (int k = 0; k < F_IN; k++) acc += X[n * F_IN + k] * W[k * 512 + j];
  O[(size_t)n * 512 + j] = acc;
}

// ---------- f32 tiled GEMM: C[M,N] = A[M,K] @ B[K,N]; K%16==0, N%64==0 ----------
#define BM 64
#define BN 64
#define BK 16
__global__ __launch_bounds__(256) void k_sgemm(const float* __restrict__ A,
                                               const float* __restrict__ B,
                                               float* __restrict__ C,
                                               int M, int N, int K) {
  __shared__ float As[BK][BM + 4];
  __shared__ float Bs[BK][BN];
  int tid = threadIdx.x;
  int bm = blockIdx.x * BM, bn = blockIdx.y * BN;
  int tx = tid & 15, ty = tid >> 4;
  int lm = tid >> 2;            // 0..63 (A row within tile)
  int lk = (tid & 3) * 4;       // 0,4,8,12
  int bkr = tid >> 4;           // 0..15 (B row within tile)
  int bkc = (tid & 15) * 4;     // 0..60
  float c[4][4] = {};
  for (int k0 = 0; k0 < K; k0 += BK) {
    float4 av;
    int gr = bm + lm;
    if (gr < M)
      av = *(const float4*)&A[(size_t)gr * K + k0 + lk];
    else
      av = make_float4(0.f, 0.f, 0.f, 0.f);
    As[lk + 0][lm] = av.x;
    As[lk + 1][lm] = av.y;
    As[lk + 2][lm] = av.z;
    As[lk + 3][lm] = av.w;
    float4 bv = *(const float4*)&B[(size_t)(k0 + bkr) * N + bn + bkc];
    Bs[bkr][bkc + 0] = bv.x;
    Bs[bkr][bkc + 1] = bv.y;
    Bs[bkr][bkc + 2] = bv.z;
    Bs[bkr][bkc + 3] = bv.w;
    __syncthreads();
#pragma unroll
    for (int kk = 0; kk < BK; kk++) {
      float4 a4 = *(const float4*)&As[kk][ty * 4];
      float4 b4 = *(const float4*)&Bs[kk][tx * 4];
      float a[4] = {a4.x, a4.y, a4.z, a4.w};
      float b[4] = {b4.x, b4.y, b4.z, b4.w};
#pragma unroll
      for (int i = 0; i < 4; i++)
#pragma unroll
        for (int j = 0; j < 4; j++) c[i][j] += a[i] * b[j];
    }
    __syncthreads();
  }
#pragma unroll
  for (int i = 0; i < 4; i++) {
    int gr = bm + ty * 4 + i;
    if (gr < M) {
#pragma unroll
      for (int j = 0; j < 4; j++) C[(size_t)gr * N + bn + tx * 4 + j] = c[i][j];
    }
  }
}

// ---------- per-node attention coefficients ----------
template <int H>
__global__ void k_alpha(const float* __restrict__ h, const float* __restrict__ a_src,
                        const float* __restrict__ a_dst, float* __restrict__ asrc,
                        float* __restrict__ adst) {
  int n = blockIdx.x;
  int w = threadIdx.x >> 6;  // head
  int lane = threadIdx.x & 63;
  const float* row = h + (size_t)n * (H * HID) + w * HID;
  float v1 = row[lane], v2 = row[lane + 64];
  float s1 = v1 * a_src[w * HID + lane] + v2 * a_src[w * HID + lane + 64];
  float s2 = v1 * a_dst[w * HID + lane] + v2 * a_dst[w * HID + lane + 64];
#pragma unroll
  for (int off = 32; off; off >>= 1) {
    s1 += __shfl_down(s1, off);
    s2 += __shfl_down(s2, off);
  }
  if (lane == 0) {
    asrc[n * H + w] = s1;
    adst[n * H + w] = s2;
  }
}

// ---------- segment softmax + aggregation (one block per dst node) ----------
template <int H, bool ELU>
__global__ void k_aggregate(const float* __restrict__ h, const float* __restrict__ asrc,
                            const float* __restrict__ adst, const int* __restrict__ row_ptr,
                            const int* __restrict__ csr_src, const float* __restrict__ bias,
                            float* __restrict__ out) {
  const int HC = H * HID;
  const int CHK = 128;
  int d = blockIdx.x;
  int t = threadIdx.x;  // blockDim == HC
  int start = row_ptr[d];
  int deg = row_ptr[d + 1] - start;
  __shared__ unsigned smax_u[H];
  __shared__ float smax[H], ssum[H], sinv[H], adst_s[H];
  __shared__ int src_l[CHK];
  __shared__ float alpha_l[CHK * H];
  if (t < H) {
    smax_u[t] = fmap(-INFINITY);
    ssum[t] = 0.f;
    adst_s[t] = adst[d * H + t];
  }
  __syncthreads();
  for (int i = t; i < deg * H; i += HC) {
    int k = i / H, hh = i - k * H;
    int s = csr_src[start + k];
    float v = lrelu(asrc[s * H + hh] + adst_s[hh]);
    atomicMax(&smax_u[hh], fmap(v));
  }
  __syncthreads();
  if (t < H) smax[t] = funmap(smax_u[t]);
  __syncthreads();
  for (int i = t; i < deg * H; i += HC) {
    int k = i / H, hh = i - k * H;
    int s = csr_src[start + k];
    float v = lrelu(asrc[s * H + hh] + adst_s[hh]);
    atomicAdd(&ssum[hh], expf(v - smax[hh]));
  }
  __syncthreads();
  if (t < H) sinv[t] = (deg > 0) ? 1.f / ssum[t] : 0.f;
  __syncthreads();
  int hh_t = t / HID;
  float acc = 0.f;
  for (int base = 0; base < deg; base += CHK) {
    int cnt = min(CHK, deg - base);
    for (int i = t; i < cnt; i += HC) src_l[i] = csr_src[start + base + i];
    __syncthreads();
    for (int i = t; i < cnt * H; i += HC) {
      int k = i / H, hh = i - k * H;
      int s = src_l[k];
      float v = lrelu(asrc[s * H + hh] + adst_s[hh]);
      alpha_l[k * H + hh] = expf(v - smax[hh]) * sinv[hh];
    }
    __syncthreads();
    for (int k = 0; k < cnt; k++) acc += alpha_l[k * H + hh_t] * h[(size_t)src_l[k] * HC + t];
    __syncthreads();
  }
  float o = acc + bias[t];
  out[(size_t)d * HC + t] = ELU ? elu1(o) : o;
}

// ---------- graph mean + heads ----------
__global__ void k_colsum(const float* __restrict__ h3, float* __restrict__ gsum) {
  int c = threadIdx.x;  // 128
  int nb = gridDim.x;
  int per = (NN + nb - 1) / nb;
  int r0 = blockIdx.x * per, r1 = min(NN, r0 + per);
  float acc = 0.f;
  for (int r = r0; r < r1; r++) acc += h3[(size_t)r * HID + c];
  atomicAdd(&gsum[c], acc);
}

__global__ void k_head(const float* __restrict__ gsum, const float* __restrict__ h3,
                       const int* __restrict__ curp, const float* __restrict__ pw1,
                       const float* __restrict__ pb1, const float* __restrict__ pw2,
                       const float* __restrict__ pb2, const float* __restrict__ vw1,
                       const float* __restrict__ vb1, const float* __restrict__ vw2,
                       const float* __restrict__ vb2, float* __restrict__ outp) {
  __shared__ float comb[HID], ph[HID], vh[HID];
  int t = threadIdx.x;  // 128
  int cur = curp[0];
  comb[t] = gsum[t] * (1.f / NN) + h3[(size_t)cur * HID + t];
  __syncthreads();
  float accp = pb1[t], accv = vb1[t];
  for (int k = 0; k < HID; k++) {
    float cv = comb[k];
    accp += cv * pw1[k * HID + t];
    accv += cv * vw1[k * HID + t];
  }
  ph[t] = fmaxf(accp, 0.f);
  vh[t] = fmaxf(accv, 0.f);
  __syncthreads();
  if (t < 6) {
    float a = pb2[t];
    for (int k = 0; k < HID; k++) a += ph[k] * pw2[k * 6 + t];
    outp[t] = a;
  }
  if (t == 6) {
    float a = vb2[0];
    for (int k = 0; k < HID; k++) a += vh[k] * vw2[k];
    outp[6] = a;
  }
}

extern "C" void kernel_launch(void* const* d_in, const int* in_sizes, int n_in,
                              void* d_out, int out_size, void* d_ws, size_t ws_size,
                              hipStream_t stream) {
  const float* x = (const float*)d_in[0];
  const int* ei = (const int*)d_in[1];
  const int* cur = (const int*)d_in[2];
  const float* W1 = (const float*)d_in[3];
  const float* as1 = (const float*)d_in[4];
  const float* ad1 = (const float*)d_in[5];
  const float* b1 = (const float*)d_in[6];
  const float* W2 = (const float*)d_in[7];
  const float* as2 = (const float*)d_in[8];
  const float* ad2 = (const float*)d_in[9];
  const float* b2 = (const float*)d_in[10];
  const float* W3 = (const float*)d_in[11];
  const float* as3 = (const float*)d_in[12];
  const float* ad3 = (const float*)d_in[13];
  const float* b3 = (const float*)d_in[14];
  const float* pw1 = (const float*)d_in[15];
  const float* pb1 = (const float*)d_in[16];
  const float* pw2 = (const float*)d_in[17];
  const float* pb2 = (const float*)d_in[18];
  const float* vw1 = (const float*)d_in[19];
  const float* vb1 = (const float*)d_in[20];
  const float* vw2 = (const float*)d_in[21];
  const float* vb2 = (const float*)d_in[22];
  float* out = (float*)d_out;

  char* w = (char*)d_ws;
  float* G = (float*)w;      w += (size_t)NN * 512 * 4;   // pre-aggregation features
  float* Abuf = (float*)w;   w += (size_t)NN * 512 * 4;   // post-aggregation features
  float* asrc = (float*)w;   w += (size_t)NN * 4 * 4;
  float* adst = (float*)w;   w += (size_t)NN * 4 * 4;
  int* deg = (int*)w;        w += (size_t)NN * 4;
  int* cursor = (int*)w;     w += (size_t)NN * 4;
  int* row_ptr = (int*)w;    w += (size_t)(NN + 1) * 4;
  int* csr_src = (int*)w;    w += (size_t)NE * 4;
  float* gsum = (float*)w;   w += (size_t)HID * 4;

  hipMemsetAsync(deg, 0, NN * 4, stream);
  hipMemsetAsync(gsum, 0, HID * 4, stream);

  // CSR by destination (rebuilt every call; edge_index is restored each run)
  k_deg<<<(NE + 255) / 256, 256, 0, stream>>>(ei, deg);
  k_scan<<<1, 1024, 0, stream>>>(deg, row_ptr, cursor);
  k_scatter<<<(NE + 255) / 256, 256, 0, stream>>>(ei, cursor, csr_src);

  // Layer 1: 11 -> 4x128
  k_gemm_fin<<<dim3(NN, 2), 256, 0, stream>>>(x, W1, G);
  k_alpha<4><<<NN, 256, 0, stream>>>(G, as1, ad1, asrc, adst);
  k_aggregate<4, true><<<NN, 512, 0, stream>>>(G, asrc, adst, row_ptr, csr_src, b1, Abuf);

  // Layer 2: 512 -> 4x128
  k_sgemm<<<dim3((NN + BM - 1) / BM, 512 / BN), 256, 0, stream>>>(Abuf, W2, G, NN, 512, 512);
  k_alpha<4><<<NN, 256, 0, stream>>>(G, as2, ad2, asrc, adst);
  k_aggregate<4, true><<<NN, 512, 0, stream>>>(G, asrc, adst, row_ptr, csr_src, b2, Abuf);

  // Layer 3: 512 -> 128 (1 head, no ELU)
  k_sgemm<<<dim3((NN + BM - 1) / BM, 128 / BN), 256, 0, stream>>>(Abuf, W3, G, NN, 128, 512);
  k_alpha<1><<<NN, 64, 0, stream>>>(G, as3, ad3, asrc, adst);
  k_aggregate<1, false><<<NN, 128, 0, stream>>>(G, asrc, adst, row_ptr, csr_src, b3, Abuf);

  // Heads
  k_colsum<<<256, 128, 0, stream>>>(Abuf, gsum);
  k_head<<<1, 128, 0, stream>>>(gsum, Abuf, cur, pw1, pb1, pw2, pb2, vw1, vb1, vw2, vb2, out);
}

// Round 2
// 963.260 us; speedup vs baseline: 1.6941x; 1.6941x over previous
//
#include <hip/hip_runtime.h>
#include <math.h>

#define NN 50000
#define NE 800000
#define F_IN 11
#define HID 128
#define NEG_SLOPE 0.2f

typedef __attribute__((ext_vector_type(8))) short short8;
typedef __attribute__((ext_vector_type(4))) float f32x4;

__device__ __forceinline__ float bf2f(ushort u) {
  return __uint_as_float(((unsigned)u) << 16);
}
__device__ __forceinline__ ushort f2bf(float f) {
  unsigned u = __float_as_uint(f);
  return (ushort)((u + 0x7fff + ((u >> 16) & 1)) >> 16);
}
__device__ __forceinline__ unsigned fmap(float f) {
  unsigned u = __float_as_uint(f);
  return (u & 0x80000000u) ? ~u : (u | 0x80000000u);
}
__device__ __forceinline__ float funmap(unsigned u) {
  return (u & 0x80000000u) ? __uint_as_float(u ^ 0x80000000u) : __uint_as_float(~u);
}
__device__ __forceinline__ float lrelu(float x) { return x > 0.f ? x : NEG_SLOPE * x; }
__device__ __forceinline__ float elu1(float x) { return x > 0.f ? x : expm1f(x); }

#define AS1 __attribute__((address_space(1)))
#define AS3 __attribute__((address_space(3)))

// ---------- CSR build ----------
__global__ void k_deg(const int* __restrict__ ei, int* __restrict__ deg) {
  int e = blockIdx.x * blockDim.x + threadIdx.x;
  if (e < NE) atomicAdd(&deg[ei[NE + e]], 1);
}

__global__ void k_scan(const int* __restrict__ deg, int* __restrict__ row_ptr,
                       int* __restrict__ cursor) {
  const int T = 1024;
  const int CH = (NN + T - 1) / T;
  __shared__ int ssum[T];
  int t = threadIdx.x;
  int base = t * CH;
  int s = 0;
  for (int i = 0; i < CH; i++) {
    int idx = base + i;
    if (idx < NN) s += deg[idx];
  }
  ssum[t] = s;
  __syncthreads();
  for (int off = 1; off < T; off <<= 1) {
    int v = (t >= off) ? ssum[t - off] : 0;
    __syncthreads();
    ssum[t] += v;
    __syncthreads();
  }
  int run = ssum[t] - s;
  for (int i = 0; i < CH; i++) {
    int idx = base + i;
    if (idx < NN) {
      row_ptr[idx] = run;
      cursor[idx] = run;
      run += deg[idx];
    }
  }
  if (t == 0) row_ptr[NN] = ssum[T - 1];
}

__global__ void k_scatter(const int* __restrict__ ei, int* __restrict__ cursor,
                          int* __restrict__ csr_src) {
  int e = blockIdx.x * blockDim.x + threadIdx.x;
  if (e < NE) {
    int d = ei[NE + e];
    int pos = atomicAdd(&cursor[d], 1);
    csr_src[pos] = ei[e];
  }
}

// ---------- weight transpose + bf16 convert: Wt[n][k] = W[k][n] ----------
__global__ void k_wt(const float* __restrict__ W, ushort* __restrict__ Wt, int K, int N) {
  __shared__ float tl[32][33];
  int bn = blockIdx.x * 32, bk = blockIdx.y * 32;
  int tx = threadIdx.x & 31, ty = threadIdx.x >> 5;  // 256 thr: ty 0..7
  for (int i = ty; i < 32; i += 8) tl[i][tx] = W[(size_t)(bk + i) * N + bn + tx];
  __syncthreads();
  for (int i = ty; i < 32; i += 8)
    Wt[(size_t)(bn + i) * K + bk + tx] = f2bf(tl[tx][i]);
}

// ---------- layer-1 GEMM (K=11), bf16 out ----------
__global__ void k_gemm_fin(const float* __restrict__ X, const float* __restrict__ W,
                           ushort* __restrict__ O) {
  int n = blockIdx.x;
  int j = blockIdx.y * 256 + threadIdx.x;
  float acc = 0.f;
#pragma unroll
  for (int k = 0; k < F_IN; k++) acc += X[n * F_IN + k] * W[k * 512 + j];
  O[(size_t)n * 512 + j] = f2bf(acc);
}

// ---------- bf16 MFMA GEMM: C[M,N] = A[M,K] @ Bt[N,K]^T ----------
// tile 128x128xK64, 256 threads (4 waves, 2x2), XOR-swizzled LDS (T2),
// global_load_lds width 16 with pre-swizzled per-lane global source (m173).
#define TM 128
#define TN 128
#define TK 64
__global__ __launch_bounds__(256) void k_mfma(const ushort* __restrict__ A,
                                              const ushort* __restrict__ Bt,
                                              ushort* __restrict__ C,
                                              int M, int N, int K) {
  __shared__ ushort lds[TM * TK + TN * TK];  // 16KB + 16KB
  ushort* As = lds;
  ushort* Bs = lds + TM * TK;
  int tid = threadIdx.x;
  int lane = tid & 63, wv = tid >> 6;
  int wr = wv >> 1, wc = wv & 1;
  int bm0 = blockIdx.x * TM, bn0 = blockIdx.y * TN;
  int l15 = lane & 15, l4 = lane >> 4;
  f32x4 acc[4][4] = {};
  for (int k0 = 0; k0 < K; k0 += TK) {
#pragma unroll
    for (int it = 0; it < 4; ++it) {
      int chunk = it * 4 + wv;       // 0..15, wave-uniform
      int pbase = chunk * 1024;      // wave-uniform LDS byte base
      int p = pbase + lane * 16;     // this lane's physical dest
      int prow = p >> 7;             // row (stride 128B)
      int lblk = ((p >> 4) & 7) ^ (prow & 7);  // logical 16B-block (inverse swizzle)
      int gr = bm0 + prow;
      gr = gr < M ? gr : M - 1;
      __builtin_amdgcn_global_load_lds(
          (const AS1 void*)(A + (size_t)gr * K + (k0 + lblk * 8)),
          (AS3 void*)((char*)As + pbase), 16, 0, 0);
      int gb = bn0 + prow;  // N % 128 == 0, always in range
      __builtin_amdgcn_global_load_lds(
          (const AS1 void*)(Bt + (size_t)gb * K + (k0 + lblk * 8)),
          (AS3 void*)((char*)Bs + pbase), 16, 0, 0);
    }
    __syncthreads();
#pragma unroll
    for (int kk = 0; kk < 2; ++kk) {
      int cb = kk * 4 + l4;
      short8 af[4], bfr[4];
#pragma unroll
      for (int m = 0; m < 4; ++m) {
        int row = wr * 64 + m * 16 + l15;
        af[m] = *(const short8*)((const char*)As + row * 128 + ((cb ^ (row & 7)) << 4));
      }
#pragma unroll
      for (int n = 0; n < 4; ++n) {
        int row = wc * 64 + n * 16 + l15;
        bfr[n] = *(const short8*)((const char*)Bs + row * 128 + ((cb ^ (row & 7)) << 4));
      }
#pragma unroll
      for (int m = 0; m < 4; ++m)
#pragma unroll
        for (int n = 0; n < 4; ++n)
          acc[m][n] = __builtin_amdgcn_mfma_f32_16x16x32_bf16(af[m], bfr[n], acc[m][n], 0, 0, 0);
    }
    __syncthreads();
  }
#pragma unroll
  for (int m = 0; m < 4; ++m) {
#pragma unroll
    for (int r = 0; r < 4; ++r) {
      int row = bm0 + wr * 64 + m * 16 + l4 * 4 + r;
      if (row < M) {
#pragma unroll
        for (int n = 0; n < 4; ++n) {
          int col = bn0 + wc * 64 + n * 16 + l15;
          C[(size_t)row * N + col] = f2bf(acc[m][n][r]);
        }
      }
    }
  }
}

// ---------- per-node attention coefficients (bf16 h) ----------
template <int H>
__global__ void k_alpha(const ushort* __restrict__ h, const float* __restrict__ a_src,
                        const float* __restrict__ a_dst, float* __restrict__ asrc,
                        float* __restrict__ adst) {
  int n = blockIdx.x;
  int w = threadIdx.x >> 6;
  int lane = threadIdx.x & 63;
  const ushort* row = h + (size_t)n * (H * HID) + w * HID;
  float v1 = bf2f(row[lane]), v2 = bf2f(row[lane + 64]);
  float s1 = v1 * a_src[w * HID + lane] + v2 * a_src[w * HID + lane + 64];
  float s2 = v1 * a_dst[w * HID + lane] + v2 * a_dst[w * HID + lane + 64];
#pragma unroll
  for (int off = 32; off; off >>= 1) {
    s1 += __shfl_down(s1, off);
    s2 += __shfl_down(s2, off);
  }
  if (lane == 0) {
    asrc[n * H + w] = s1;
    adst[n * H + w] = s2;
  }
}

// ---------- segment softmax + aggregation, H=4 (256 thr, ushort2) ----------
template <bool ELU>
__global__ __launch_bounds__(256) void k_aggregate4(
    const ushort* __restrict__ h, const float* __restrict__ asrc,
    const float* __restrict__ adst, const int* __restrict__ row_ptr,
    const int* __restrict__ csr_src, const float* __restrict__ bias,
    ushort* __restrict__ out) {
  const int HC = 512, CHK = 128;
  int d = blockIdx.x;
  int t = threadIdx.x;
  int start = row_ptr[d];
  int deg = row_ptr[d + 1] - start;
  __shared__ unsigned smax_u[4];
  __shared__ float smax[4], ssum[4], sinv[4], adst_s[4];
  __shared__ int src_l[CHK];
  __shared__ float alpha_l[CHK * 4];
  if (t < 4) {
    smax_u[t] = fmap(-INFINITY);
    ssum[t] = 0.f;
    adst_s[t] = adst[d * 4 + t];
  }
  __syncthreads();
  for (int i = t; i < deg * 4; i += 256) {
    int k = i >> 2, hh = i & 3;
    float v = lrelu(asrc[csr_src[start + k] * 4 + hh] + adst_s[hh]);
    atomicMax(&smax_u[hh], fmap(v));
  }
  __syncthreads();
  if (t < 4) smax[t] = funmap(smax_u[t]);
  __syncthreads();
  for (int i = t; i < deg * 4; i += 256) {
    int k = i >> 2, hh = i & 3;
    float v = lrelu(asrc[csr_src[start + k] * 4 + hh] + adst_s[hh]);
    atomicAdd(&ssum[hh], expf(v - smax[hh]));
  }
  __syncthreads();
  if (t < 4) sinv[t] = deg ? 1.f / ssum[t] : 0.f;
  __syncthreads();
  int hh_t = t >> 6;  // cols 2t,2t+1 -> head (2t)/128
  float ax = 0.f, ay = 0.f;
  for (int base = 0; base < deg; base += CHK) {
    int cnt = min(CHK, deg - base);
    for (int i = t; i < cnt; i += 256) src_l[i] = csr_src[start + base + i];
    __syncthreads();
    for (int i = t; i < cnt * 4; i += 256) {
      int k = i >> 2, hh = i & 3;
      float v = lrelu(asrc[src_l[k] * 4 + hh] + adst_s[hh]);
      alpha_l[(k << 2) + hh] = expf(v - smax[hh]) * sinv[hh];
    }
    __syncthreads();
    for (int k = 0; k < cnt; k++) {
      float a = alpha_l[(k << 2) + hh_t];
      unsigned hv = *(const unsigned*)(h + (size_t)src_l[k] * HC + 2 * t);
      ax += a * bf2f((ushort)(hv & 0xffff));
      ay += a * bf2f((ushort)(hv >> 16));
    }
    __syncthreads();
  }
  float o0 = ax + bias[2 * t], o1 = ay + bias[2 * t + 1];
  out[(size_t)d * HC + 2 * t] = f2bf(ELU ? elu1(o0) : o0);
  out[(size_t)d * HC + 2 * t + 1] = f2bf(ELU ? elu1(o1) : o1);
}

// ---------- segment softmax + aggregation, H=1 (128 thr) ----------
__global__ __launch_bounds__(128) void k_aggregate1(
    const ushort* __restrict__ h, const float* __restrict__ asrc,
    const float* __restrict__ adst, const int* __restrict__ row_ptr,
    const int* __restrict__ csr_src, const float* __restrict__ bias,
    ushort* __restrict__ out) {
  const int CHK = 128;
  int d = blockIdx.x;
  int t = threadIdx.x;
  int start = row_ptr[d];
  int deg = row_ptr[d + 1] - start;
  __shared__ unsigned smax_u;
  __shared__ float smax, ssum, sinv, adst_s;
  __shared__ int src_l[CHK];
  __shared__ float alpha_l[CHK];
  if (t == 0) {
    smax_u = fmap(-INFINITY);
    ssum = 0.f;
    adst_s = adst[d];
  }
  __syncthreads();
  for (int i = t; i < deg; i += 128)
    atomicMax(&smax_u, fmap(lrelu(asrc[csr_src[start + i]] + adst_s)));
  __syncthreads();
  if (t == 0) smax = funmap(smax_u);
  __syncthreads();
  for (int i = t; i < deg; i += 128)
    atomicAdd(&ssum, expf(lrelu(asrc[csr_src[start + i]] + adst_s) - smax));
  __syncthreads();
  if (t == 0) sinv = deg ? 1.f / ssum : 0.f;
  __syncthreads();
  float acc = 0.f;
  for (int base = 0; base < deg; base += CHK) {
    int cnt = min(CHK, deg - base);
    for (int i = t; i < cnt; i += 128) {
      int s = csr_src[start + base + i];
      src_l[i] = s;
      alpha_l[i] = expf(lrelu(asrc[s] + adst_s) - smax) * sinv;
    }
    __syncthreads();
    for (int k = 0; k < cnt; k++) acc += alpha_l[k] * bf2f(h[(size_t)src_l[k] * HID + t]);
    __syncthreads();
  }
  out[(size_t)d * HID + t] = f2bf(acc + bias[t]);
}

// ---------- graph mean + heads ----------
__global__ void k_colsum(const ushort* __restrict__ h3, float* __restrict__ gsum) {
  int c = threadIdx.x;  // 128
  int nb = gridDim.x;
  int per = (NN + nb - 1) / nb;
  int r0 = blockIdx.x * per, r1 = min(NN, r0 + per);
  float acc = 0.f;
  for (int r = r0; r < r1; r++) acc += bf2f(h3[(size_t)r * HID + c]);
  atomicAdd(&gsum[c], acc);
}

__global__ void k_head(const float* __restrict__ gsum, const ushort* __restrict__ h3,
                       const int* __restrict__ curp, const float* __restrict__ pw1,
                       const float* __restrict__ pb1, const float* __restrict__ pw2,
                       const float* __restrict__ pb2, const float* __restrict__ vw1,
                       const float* __restrict__ vb1, const float* __restrict__ vw2,
                       const float* __restrict__ vb2, float* __restrict__ outp) {
  __shared__ float comb[HID], ph[HID], vh[HID];
  int t = threadIdx.x;  // 128
  int cur = curp[0];
  comb[t] = gsum[t] * (1.f / NN) + bf2f(h3[(size_t)cur * HID + t]);
  __syncthreads();
  float accp = pb1[t], accv = vb1[t];
  for (int k = 0; k < HID; k++) {
    float cv = comb[k];
    accp += cv * pw1[k * HID + t];
    accv += cv * vw1[k * HID + t];
  }
  ph[t] = fmaxf(accp, 0.f);
  vh[t] = fmaxf(accv, 0.f);
  __syncthreads();
  if (t < 6) {
    float a = pb2[t];
    for (int k = 0; k < HID; k++) a += ph[k] * pw2[k * 6 + t];
    outp[t] = a;
  }
  if (t == 6) {
    float a = vb2[0];
    for (int k = 0; k < HID; k++) a += vh[k] * vw2[k];
    outp[6] = a;
  }
}

extern "C" void kernel_launch(void* const* d_in, const int* in_sizes, int n_in,
                              void* d_out, int out_size, void* d_ws, size_t ws_size,
                              hipStream_t stream) {
  const float* x = (const float*)d_in[0];
  const int* ei = (const int*)d_in[1];
  const int* cur = (const int*)d_in[2];
  const float* W1 = (const float*)d_in[3];
  const float* as1 = (const float*)d_in[4];
  const float* ad1 = (const float*)d_in[5];
  const float* b1 = (const float*)d_in[6];
  const float* W2 = (const float*)d_in[7];
  const float* as2 = (const float*)d_in[8];
  const float* ad2 = (const float*)d_in[9];
  const float* b2 = (const float*)d_in[10];
  const float* W3 = (const float*)d_in[11];
  const float* as3 = (const float*)d_in[12];
  const float* ad3 = (const float*)d_in[13];
  const float* b3 = (const float*)d_in[14];
  const float* pw1 = (const float*)d_in[15];
  const float* pb1 = (const float*)d_in[16];
  const float* pw2 = (const float*)d_in[17];
  const float* pb2 = (const float*)d_in[18];
  const float* vw1 = (const float*)d_in[19];
  const float* vb1 = (const float*)d_in[20];
  const float* vw2 = (const float*)d_in[21];
  const float* vb2 = (const float*)d_in[22];
  float* out = (float*)d_out;

  char* w = (char*)d_ws;
  ushort* G = (ushort*)w;    w += (size_t)NN * 512 * 2;      // pre-agg features (bf16)
  ushort* Abuf = (ushort*)w; w += (size_t)NN * 512 * 2;      // post-agg features (bf16)
  ushort* Wt2 = (ushort*)w;  w += (size_t)512 * 512 * 2;     // W2^T bf16
  ushort* Wt3 = (ushort*)w;  w += (size_t)128 * 512 * 2;     // W3^T bf16
  float* asrc = (float*)w;   w += (size_t)NN * 4 * 4;
  float* adst = (float*)w;   w += (size_t)NN * 4 * 4;
  int* deg = (int*)w;        w += (size_t)NN * 4;
  int* cursor = (int*)w;     w += (size_t)NN * 4;
  int* row_ptr = (int*)w;    w += (size_t)(NN + 1) * 4;
  int* csr_src = (int*)w;    w += (size_t)NE * 4;
  float* gsum = (float*)w;   w += (size_t)HID * 4;

  hipMemsetAsync(deg, 0, NN * 4, stream);
  hipMemsetAsync(gsum, 0, HID * 4, stream);

  // CSR by destination
  k_deg<<<(NE + 255) / 256, 256, 0, stream>>>(ei, deg);
  k_scan<<<1, 1024, 0, stream>>>(deg, row_ptr, cursor);
  k_scatter<<<(NE + 255) / 256, 256, 0, stream>>>(ei, cursor, csr_src);

  // W2^T, W3^T (bf16)
  k_wt<<<dim3(512 / 32, 512 / 32), 256, 0, stream>>>(W2, Wt2, 512, 512);
  k_wt<<<dim3(128 / 32, 512 / 32), 256, 0, stream>>>(W3, Wt3, 512, 128);

  const int GB = (NN + TM - 1) / TM;  // 391

  // Layer 1: 11 -> 4x128
  k_gemm_fin<<<dim3(NN, 2), 256, 0, stream>>>(x, W1, G);
  k_alpha<4><<<NN, 256, 0, stream>>>(G, as1, ad1, asrc, adst);
  k_aggregate4<true><<<NN, 256, 0, stream>>>(G, asrc, adst, row_ptr, csr_src, b1, Abuf);

  // Layer 2: 512 -> 4x128 (bf16 MFMA)
  k_mfma<<<dim3(GB, 4), 256, 0, stream>>>(Abuf, Wt2, G, NN, 512, 512);
  k_alpha<4><<<NN, 256, 0, stream>>>(G, as2, ad2, asrc, adst);
  k_aggregate4<true><<<NN, 256, 0, stream>>>(G, asrc, adst, row_ptr, csr_src, b2, Abuf);

  // Layer 3: 512 -> 128 (bf16 MFMA)
  k_mfma<<<dim3(GB, 1), 256, 0, stream>>>(Abuf, Wt3, G, NN, 128, 512);
  k_alpha<1><<<NN, 64, 0, stream>>>(G, as3, ad3, asrc, adst);
  k_aggregate1<<<NN, 128, 0, stream>>>(G, asrc, adst, row_ptr, csr_src, b3, Abuf);

  // Heads
  k_colsum<<<256, 128, 0, stream>>>(Abuf, gsum);
  k_head<<<1, 128, 0, stream>>>(gsum, Abuf, cur, pw1, pb1, pw2, pb2, vw1, vb1, vw2, vb2, out);
}

// Round 4
// 846.020 us; speedup vs baseline: 1.9289x; 1.1386x over previous
//
#include <hip/hip_runtime.h>
#include <math.h>

#define NN 50000
#define NE 800000
#define F_IN 11
#define HID 128
#define NEG_SLOPE 0.2f

typedef __attribute__((ext_vector_type(8))) short short8;
typedef __attribute__((ext_vector_type(4))) float f32x4;

__device__ __forceinline__ float bf2f(ushort u) {
  return __uint_as_float(((unsigned)u) << 16);
}
__device__ __forceinline__ ushort f2bf(float f) {
  unsigned u = __float_as_uint(f);
  return (ushort)((u + 0x7fff + ((u >> 16) & 1)) >> 16);
}
__device__ __forceinline__ float lrelu(float x) { return x > 0.f ? x : NEG_SLOPE * x; }
__device__ __forceinline__ float elu1(float x) { return x > 0.f ? x : expm1f(x); }

// finite "-inf" so online-softmax merges of empty lanes never produce
// (-inf) - (-inf) = NaN inside __expf  (round-3 bug: s = 0*NaN poisoned
// every node with deg*4 < blockDim, i.e. nearly all of them)
#define MNEG (-1e30f)

#define AS1 __attribute__((address_space(1)))
#define AS3 __attribute__((address_space(3)))

// ---------- CSR build ----------
__global__ void k_deg(const int* __restrict__ ei, int* __restrict__ deg) {
  int e = blockIdx.x * blockDim.x + threadIdx.x;
  if (e < NE) atomicAdd(&deg[ei[NE + e]], 1);
}

__global__ void k_scan(const int* __restrict__ deg, int* __restrict__ row_ptr,
                       int* __restrict__ cursor) {
  const int T = 1024;
  const int CH = (NN + T - 1) / T;
  __shared__ int ssum[T];
  int t = threadIdx.x;
  int base = t * CH;
  int s = 0;
  for (int i = 0; i < CH; i++) {
    int idx = base + i;
    if (idx < NN) s += deg[idx];
  }
  ssum[t] = s;
  __syncthreads();
  for (int off = 1; off < T; off <<= 1) {
    int v = (t >= off) ? ssum[t - off] : 0;
    __syncthreads();
    ssum[t] += v;
    __syncthreads();
  }
  int run = ssum[t] - s;
  for (int i = 0; i < CH; i++) {
    int idx = base + i;
    if (idx < NN) {
      row_ptr[idx] = run;
      cursor[idx] = run;
      run += deg[idx];
    }
  }
  if (t == 0) row_ptr[NN] = ssum[T - 1];
}

__global__ void k_scatter(const int* __restrict__ ei, int* __restrict__ cursor,
                          int* __restrict__ csr_src) {
  int e = blockIdx.x * blockDim.x + threadIdx.x;
  if (e < NE) {
    int d = ei[NE + e];
    int pos = atomicAdd(&cursor[d], 1);
    csr_src[pos] = ei[e];
  }
}

// ---------- weight transpose + bf16 convert: Wt[n][k] = W[k][n] ----------
__global__ void k_wt(const float* __restrict__ W, ushort* __restrict__ Wt, int K, int N) {
  __shared__ float tl[32][33];
  int bn = blockIdx.x * 32, bk = blockIdx.y * 32;
  int tx = threadIdx.x & 31, ty = threadIdx.x >> 5;
  for (int i = ty; i < 32; i += 8) tl[i][tx] = W[(size_t)(bk + i) * N + bn + tx];
  __syncthreads();
  for (int i = ty; i < 32; i += 8)
    Wt[(size_t)(bn + i) * K + bk + tx] = f2bf(tl[tx][i]);
}

// ---------- layer-1 GEMM (K=11), packed bf16 out ----------
__global__ void k_gemm_fin(const float* __restrict__ X, const float* __restrict__ W,
                           ushort* __restrict__ O) {
  int n = blockIdx.x;
  int t = threadIdx.x;  // 256
  float x[F_IN];
#pragma unroll
  for (int k = 0; k < F_IN; k++) x[k] = X[n * F_IN + k];
  float a0 = 0.f, a1 = 0.f;
#pragma unroll
  for (int k = 0; k < F_IN; k++) {
    float2 wv = *(const float2*)(W + k * 512 + 2 * t);
    a0 += x[k] * wv.x;
    a1 += x[k] * wv.y;
  }
  unsigned pk = (unsigned)f2bf(a0) | ((unsigned)f2bf(a1) << 16);
  *(unsigned*)(O + (size_t)n * 512 + 2 * t) = pk;
}

// ---------- bf16 MFMA GEMM: C[M,N] = A[M,K] @ Bt[N,K]^T ----------
#define TM 128
#define TN 128
#define TK 64
__global__ __launch_bounds__(256) void k_mfma(const ushort* __restrict__ A,
                                              const ushort* __restrict__ Bt,
                                              ushort* __restrict__ C,
                                              int M, int N, int K) {
  __shared__ ushort lds[TM * TK + TN * TK];
  ushort* As = lds;
  ushort* Bs = lds + TM * TK;
  int tid = threadIdx.x;
  int lane = tid & 63, wv = tid >> 6;
  int wr = wv >> 1, wc = wv & 1;
  int bm0 = blockIdx.x * TM, bn0 = blockIdx.y * TN;
  int l15 = lane & 15, l4 = lane >> 4;
  f32x4 acc[4][4] = {};
  for (int k0 = 0; k0 < K; k0 += TK) {
#pragma unroll
    for (int it = 0; it < 4; ++it) {
      int chunk = it * 4 + wv;
      int pbase = chunk * 1024;
      int p = pbase + lane * 16;
      int prow = p >> 7;
      int lblk = ((p >> 4) & 7) ^ (prow & 7);
      int gr = bm0 + prow;
      gr = gr < M ? gr : M - 1;
      __builtin_amdgcn_global_load_lds(
          (const AS1 void*)(A + (size_t)gr * K + (k0 + lblk * 8)),
          (AS3 void*)((char*)As + pbase), 16, 0, 0);
      int gb = bn0 + prow;
      __builtin_amdgcn_global_load_lds(
          (const AS1 void*)(Bt + (size_t)gb * K + (k0 + lblk * 8)),
          (AS3 void*)((char*)Bs + pbase), 16, 0, 0);
    }
    __syncthreads();
#pragma unroll
    for (int kk = 0; kk < 2; ++kk) {
      int cb = kk * 4 + l4;
      short8 af[4], bfr[4];
#pragma unroll
      for (int m = 0; m < 4; ++m) {
        int row = wr * 64 + m * 16 + l15;
        af[m] = *(const short8*)((const char*)As + row * 128 + ((cb ^ (row & 7)) << 4));
      }
#pragma unroll
      for (int n = 0; n < 4; ++n) {
        int row = wc * 64 + n * 16 + l15;
        bfr[n] = *(const short8*)((const char*)Bs + row * 128 + ((cb ^ (row & 7)) << 4));
      }
#pragma unroll
      for (int m = 0; m < 4; ++m)
#pragma unroll
        for (int n = 0; n < 4; ++n)
          acc[m][n] = __builtin_amdgcn_mfma_f32_16x16x32_bf16(af[m], bfr[n], acc[m][n], 0, 0, 0);
    }
    __syncthreads();
  }
#pragma unroll
  for (int m = 0; m < 4; ++m) {
#pragma unroll
    for (int r = 0; r < 4; ++r) {
      int row = bm0 + wr * 64 + m * 16 + l4 * 4 + r;
      if (row < M) {
#pragma unroll
        for (int n = 0; n < 4; ++n) {
          int col = bn0 + wc * 64 + n * 16 + l15;
          C[(size_t)row * N + col] = f2bf(acc[m][n][r]);
        }
      }
    }
  }
}

// ---------- attention coefficients: 16-lane group per (node, head) ----------
template <int H>
__global__ void k_alpha(const ushort* __restrict__ h, const float* __restrict__ a_src,
                        const float* __restrict__ a_dst, float* __restrict__ asrc,
                        float* __restrict__ adst) {
  int t = threadIdx.x;  // 256
  int lane = t & 63;
  int n_g, h_g;
  if (H == 4) {
    n_g = blockIdx.x * 4 + (t >> 6);
    h_g = lane >> 4;
  } else {
    n_g = blockIdx.x * 16 + (t >> 4);
    h_g = 0;
  }
  if (n_g >= NN) return;
  int cl = lane & 15;
  short8 hv = *(const short8*)(h + (size_t)n_g * (H * 128) + h_g * 128 + cl * 8);
  const float* as = a_src + h_g * 128 + cl * 8;
  const float* ad = a_dst + h_g * 128 + cl * 8;
  float s1 = 0.f, s2 = 0.f;
#pragma unroll
  for (int j = 0; j < 8; j++) {
    float v = bf2f((ushort)hv[j]);
    s1 += v * as[j];
    s2 += v * ad[j];
  }
#pragma unroll
  for (int off = 1; off < 16; off <<= 1) {
    s1 += __shfl_xor(s1, off);
    s2 += __shfl_xor(s2, off);
  }
  if (cl == 0) {
    asrc[n_g * H + h_g] = s1;
    adst[n_g * H + h_g] = s2;
  }
}

// ---------- aggregation H=4: online softmax + wave-per-edge 16B gather ----------
template <bool ELU>
__global__ __launch_bounds__(256) void k_aggregate4(
    const ushort* __restrict__ h, const float* __restrict__ asrc,
    const float* __restrict__ adst, const int* __restrict__ row_ptr,
    const int* __restrict__ csr_src, const float* __restrict__ bias,
    ushort* __restrict__ out) {
  const int ECAP = 256;
  int d = blockIdx.x;
  int t = threadIdx.x;
  int lane = t & 63, wv = t >> 6;
  int start = row_ptr[d];
  int deg = row_ptr[d + 1] - start;
  __shared__ int src_l[ECAP];
  __shared__ float e_l[ECAP * 4];
  __shared__ float redm[16], reds[16];
  __shared__ float smax[4], sinv[4];
  __shared__ float partial[4 * 512];
  int dcap = min(deg, ECAP);
  for (int i = t; i < dcap; i += 256) src_l[i] = csr_src[start + i];
  __syncthreads();
  // pass 1: e-values + online (max,sum); thread handles (edge,head), head = t&3
  int hh = t & 3;
  float adh = adst[d * 4 + hh];
  float m = MNEG, s = 0.f;
  for (int i = t; i < deg * 4; i += 256) {
    int k = i >> 2;
    int sn = (k < ECAP) ? src_l[k] : csr_src[start + k];
    float v = lrelu(asrc[sn * 4 + hh] + adh);
    if (k < ECAP) e_l[i] = v;
    float nm = fmaxf(m, v);
    s = s * __expf(m - nm) + __expf(v - nm);
    m = nm;
  }
#pragma unroll
  for (int off = 4; off < 64; off <<= 1) {
    float m2 = __shfl_xor(m, off);
    float s2 = __shfl_xor(s, off);
    float nm = fmaxf(m, m2);
    s = s * __expf(m - nm) + s2 * __expf(m2 - nm);
    m = nm;
  }
  if (lane < 4) {
    redm[wv * 4 + lane] = m;
    reds[wv * 4 + lane] = s;
  }
  __syncthreads();
  if (t < 4) {
    float mm = redm[t], ss = reds[t];
#pragma unroll
    for (int w2 = 1; w2 < 4; w2++) {
      float m2 = redm[w2 * 4 + t], s2 = reds[w2 * 4 + t];
      float nm = fmaxf(mm, m2);
      ss = ss * __expf(mm - nm) + s2 * __expf(m2 - nm);
      mm = nm;
    }
    smax[t] = mm;
    sinv[t] = (ss > 0.f) ? 1.f / ss : 0.f;
  }
  __syncthreads();
  // pass 2: wave wv handles edges wv, wv+4, ...; lane covers cols lane*8..+7
  int hl = lane >> 4;
  float mh = smax[hl], sih = sinv[hl];
  float acc[8] = {};
  for (int k = wv; k < deg; k += 4) {
    int sn;
    float ev;
    if (k < ECAP) {
      sn = src_l[k];
      ev = e_l[k * 4 + hl];
    } else {
      sn = csr_src[start + k];
      ev = lrelu(asrc[sn * 4 + hl] + adst[d * 4 + hl]);
    }
    float a = __expf(ev - mh) * sih;
    short8 hv = *(const short8*)(h + (size_t)sn * 512 + lane * 8);
#pragma unroll
    for (int j = 0; j < 8; j++) acc[j] += a * bf2f((ushort)hv[j]);
  }
#pragma unroll
  for (int j = 0; j < 8; j++) partial[wv * 512 + lane * 8 + j] = acc[j];
  __syncthreads();
  float2 b2 = *(const float2*)(bias + 2 * t);
  float o0 = b2.x, o1 = b2.y;
#pragma unroll
  for (int w2 = 0; w2 < 4; w2++) {
    float2 p = *(const float2*)(partial + w2 * 512 + 2 * t);
    o0 += p.x;
    o1 += p.y;
  }
  if (ELU) {
    o0 = elu1(o0);
    o1 = elu1(o1);
  }
  unsigned pk = (unsigned)f2bf(o0) | ((unsigned)f2bf(o1) << 16);
  *(unsigned*)(out + (size_t)d * 512 + 2 * t) = pk;
}

// ---------- aggregation H=1: 16-lane group per edge ----------
__global__ __launch_bounds__(256) void k_aggregate1(
    const ushort* __restrict__ h, const float* __restrict__ asrc,
    const float* __restrict__ adst, const int* __restrict__ row_ptr,
    const int* __restrict__ csr_src, const float* __restrict__ bias,
    ushort* __restrict__ out) {
  const int ECAP = 256;
  int d = blockIdx.x;
  int t = threadIdx.x;
  int lane = t & 63, wv = t >> 6;
  int slot = lane >> 4, cl = lane & 15;
  int start = row_ptr[d];
  int deg = row_ptr[d + 1] - start;
  __shared__ int src_l[ECAP];
  __shared__ float e_l[ECAP];
  __shared__ float redm[4], reds[4];
  __shared__ float smax1, sinv1;
  __shared__ float partial[16 * 128];
  __shared__ float sred[128];
  int dcap = min(deg, ECAP);
  for (int i = t; i < dcap; i += 256) src_l[i] = csr_src[start + i];
  __syncthreads();
  float adh = adst[d];
  float m = MNEG, s = 0.f;
  for (int i = t; i < deg; i += 256) {
    int sn = (i < ECAP) ? src_l[i] : csr_src[start + i];
    float v = lrelu(asrc[sn] + adh);
    if (i < ECAP) e_l[i] = v;
    float nm = fmaxf(m, v);
    s = s * __expf(m - nm) + __expf(v - nm);
    m = nm;
  }
#pragma unroll
  for (int off = 1; off < 64; off <<= 1) {
    float m2 = __shfl_xor(m, off);
    float s2 = __shfl_xor(s, off);
    float nm = fmaxf(m, m2);
    s = s * __expf(m - nm) + s2 * __expf(m2 - nm);
    m = nm;
  }
  if (lane == 0) {
    redm[wv] = m;
    reds[wv] = s;
  }
  __syncthreads();
  if (t == 0) {
    float mm = redm[0], ss = reds[0];
#pragma unroll
    for (int w2 = 1; w2 < 4; w2++) {
      float nm = fmaxf(mm, redm[w2]);
      ss = ss * __expf(mm - nm) + reds[w2] * __expf(redm[w2] - nm);
      mm = nm;
    }
    smax1 = mm;
    sinv1 = (ss > 0.f) ? 1.f / ss : 0.f;
  }
  __syncthreads();
  float mh = smax1, sih = sinv1;
  float acc[8] = {};
  for (int kb = wv * 4; kb < deg; kb += 16) {
    int k = kb + slot;
    if (k < deg) {
      int sn;
      float ev;
      if (k < ECAP) {
        sn = src_l[k];
        ev = e_l[k];
      } else {
        sn = csr_src[start + k];
        ev = lrelu(asrc[sn] + adh);
      }
      float a = __expf(ev - mh) * sih;
      short8 hv = *(const short8*)(h + (size_t)sn * 128 + cl * 8);
#pragma unroll
      for (int j = 0; j < 8; j++) acc[j] += a * bf2f((ushort)hv[j]);
    }
  }
  int p = wv * 4 + slot;
#pragma unroll
  for (int j = 0; j < 8; j++) partial[p * 128 + cl * 8 + j] = acc[j];
  __syncthreads();
  if (t < 128) {
    float o = bias[t];
    for (int q = 0; q < 16; q++) o += partial[q * 128 + t];
    sred[t] = o;
  }
  __syncthreads();
  if (t < 64) {
    unsigned pk = (unsigned)f2bf(sred[2 * t]) | ((unsigned)f2bf(sred[2 * t + 1]) << 16);
    *(unsigned*)(out + (size_t)d * 128 + 2 * t) = pk;
  }
}

// ---------- graph mean + heads ----------
__global__ __launch_bounds__(256) void k_colsum(const ushort* __restrict__ h3,
                                                float* __restrict__ gsum) {
  __shared__ float partial[16 * 128];
  int t = threadIdx.x;
  int rg = t >> 4, cl = t & 15;
  int nb = gridDim.x;
  int per = (NN + nb - 1) / nb;
  int r0 = blockIdx.x * per, r1 = min(NN, r0 + per);
  float acc[8] = {};
  for (int r = r0 + rg; r < r1; r += 16) {
    short8 hv = *(const short8*)(h3 + (size_t)r * 128 + cl * 8);
#pragma unroll
    for (int j = 0; j < 8; j++) acc[j] += bf2f((ushort)hv[j]);
  }
#pragma unroll
  for (int j = 0; j < 8; j++) partial[rg * 128 + cl * 8 + j] = acc[j];
  __syncthreads();
  if (t < 128) {
    float s = 0.f;
    for (int q = 0; q < 16; q++) s += partial[q * 128 + t];
    atomicAdd(&gsum[t], s);
  }
}

__global__ void k_head(const float* __restrict__ gsum, const ushort* __restrict__ h3,
                       const int* __restrict__ curp, const float* __restrict__ pw1,
                       const float* __restrict__ pb1, const float* __restrict__ pw2,
                       const float* __restrict__ pb2, const float* __restrict__ vw1,
                       const float* __restrict__ vb1, const float* __restrict__ vw2,
                       const float* __restrict__ vb2, float* __restrict__ outp) {
  __shared__ float comb[HID], ph[HID], vh[HID];
  int t = threadIdx.x;  // 128
  int cur = curp[0];
  comb[t] = gsum[t] * (1.f / NN) + bf2f(h3[(size_t)cur * HID + t]);
  __syncthreads();
  float accp = pb1[t], accv = vb1[t];
  for (int k = 0; k < HID; k++) {
    float cv = comb[k];
    accp += cv * pw1[k * HID + t];
    accv += cv * vw1[k * HID + t];
  }
  ph[t] = fmaxf(accp, 0.f);
  vh[t] = fmaxf(accv, 0.f);
  __syncthreads();
  if (t < 6) {
    float a = pb2[t];
    for (int k = 0; k < HID; k++) a += ph[k] * pw2[k * 6 + t];
    outp[t] = a;
  }
  if (t == 6) {
    float a = vb2[0];
    for (int k = 0; k < HID; k++) a += vh[k] * vw2[k];
    outp[6] = a;
  }
}

extern "C" void kernel_launch(void* const* d_in, const int* in_sizes, int n_in,
                              void* d_out, int out_size, void* d_ws, size_t ws_size,
                              hipStream_t stream) {
  const float* x = (const float*)d_in[0];
  const int* ei = (const int*)d_in[1];
  const int* cur = (const int*)d_in[2];
  const float* W1 = (const float*)d_in[3];
  const float* as1 = (const float*)d_in[4];
  const float* ad1 = (const float*)d_in[5];
  const float* b1 = (const float*)d_in[6];
  const float* W2 = (const float*)d_in[7];
  const float* as2 = (const float*)d_in[8];
  const float* ad2 = (const float*)d_in[9];
  const float* b2 = (const float*)d_in[10];
  const float* W3 = (const float*)d_in[11];
  const float* as3 = (const float*)d_in[12];
  const float* ad3 = (const float*)d_in[13];
  const float* b3 = (const float*)d_in[14];
  const float* pw1 = (const float*)d_in[15];
  const float* pb1 = (const float*)d_in[16];
  const float* pw2 = (const float*)d_in[17];
  const float* pb2 = (const float*)d_in[18];
  const float* vw1 = (const float*)d_in[19];
  const float* vb1 = (const float*)d_in[20];
  const float* vw2 = (const float*)d_in[21];
  const float* vb2 = (const float*)d_in[22];
  float* out = (float*)d_out;

  char* w = (char*)d_ws;
  ushort* G = (ushort*)w;    w += (size_t)NN * 512 * 2;
  ushort* Abuf = (ushort*)w; w += (size_t)NN * 512 * 2;
  ushort* Wt2 = (ushort*)w;  w += (size_t)512 * 512 * 2;
  ushort* Wt3 = (ushort*)w;  w += (size_t)128 * 512 * 2;
  float* asrc = (float*)w;   w += (size_t)NN * 4 * 4;
  float* adst = (float*)w;   w += (size_t)NN * 4 * 4;
  int* deg = (int*)w;        w += (size_t)NN * 4;
  int* cursor = (int*)w;     w += (size_t)NN * 4;
  int* row_ptr = (int*)w;    w += (size_t)(NN + 1) * 4;
  int* csr_src = (int*)w;    w += (size_t)NE * 4;
  float* gsum = (float*)w;   w += (size_t)HID * 4;

  hipMemsetAsync(deg, 0, NN * 4, stream);
  hipMemsetAsync(gsum, 0, HID * 4, stream);

  k_deg<<<(NE + 255) / 256, 256, 0, stream>>>(ei, deg);
  k_scan<<<1, 1024, 0, stream>>>(deg, row_ptr, cursor);
  k_scatter<<<(NE + 255) / 256, 256, 0, stream>>>(ei, cursor, csr_src);

  k_wt<<<dim3(512 / 32, 512 / 32), 256, 0, stream>>>(W2, Wt2, 512, 512);
  k_wt<<<dim3(128 / 32, 512 / 32), 256, 0, stream>>>(W3, Wt3, 512, 128);

  const int GB = (NN + TM - 1) / TM;  // 391

  // Layer 1: 11 -> 4x128
  k_gemm_fin<<<NN, 256, 0, stream>>>(x, W1, G);
  k_alpha<4><<<(NN + 3) / 4, 256, 0, stream>>>(G, as1, ad1, asrc, adst);
  k_aggregate4<true><<<NN, 256, 0, stream>>>(G, asrc, adst, row_ptr, csr_src, b1, Abuf);

  // Layer 2: 512 -> 4x128 (bf16 MFMA)
  k_mfma<<<dim3(GB, 4), 256, 0, stream>>>(Abuf, Wt2, G, NN, 512, 512);
  k_alpha<4><<<(NN + 3) / 4, 256, 0, stream>>>(G, as2, ad2, asrc, adst);
  k_aggregate4<true><<<NN, 256, 0, stream>>>(G, asrc, adst, row_ptr, csr_src, b2, Abuf);

  // Layer 3: 512 -> 128 (bf16 MFMA)
  k_mfma<<<dim3(GB, 1), 256, 0, stream>>>(Abuf, Wt3, G, NN, 128, 512);
  k_alpha<1><<<(NN + 15) / 16, 256, 0, stream>>>(G, as3, ad3, asrc, adst);
  k_aggregate1<<<NN, 256, 0, stream>>>(G, asrc, adst, row_ptr, csr_src, b3, Abuf);

  // Heads
  k_colsum<<<256, 128 * 2, 0, stream>>>(Abuf, gsum);
  k_head<<<1, 128, 0, stream>>>(gsum, Abuf, cur, pw1, pb1, pw2, pb2, vw1, vb1, vw2, vb2, out);
}

// Round 5
// 668.548 us; speedup vs baseline: 2.4409x; 1.2655x over previous
//
#include <hip/hip_runtime.h>
#include <math.h>

#define NN 50000
#define NE 800000
#define F_IN 11
#define HID 128
#define NEG_SLOPE 0.2f

typedef __attribute__((ext_vector_type(8))) short short8;
typedef __attribute__((ext_vector_type(4))) float f32x4;

__device__ __forceinline__ float bf2f(ushort u) {
  return __uint_as_float(((unsigned)u) << 16);
}
__device__ __forceinline__ ushort f2bf(float f) {
  unsigned u = __float_as_uint(f);
  return (ushort)((u + 0x7fff + ((u >> 16) & 1)) >> 16);
}
__device__ __forceinline__ float lrelu(float x) { return x > 0.f ? x : NEG_SLOPE * x; }
__device__ __forceinline__ float elu1(float x) { return x > 0.f ? x : expm1f(x); }

// finite "-inf": online-softmax merges of empty lanes must never form inf-inf=NaN
#define MNEG (-1e30f)

// order own-wave ds_writes before cross-lane ds_reads (no cross-wave sync needed)
__device__ __forceinline__ void wave_fence() {
  asm volatile("s_waitcnt lgkmcnt(0)" ::: "memory");
}

#define AS1 __attribute__((address_space(1)))
#define AS3 __attribute__((address_space(3)))

// ---------- CSR build ----------
__global__ void k_deg(const int* __restrict__ ei, int* __restrict__ deg) {
  int e = blockIdx.x * blockDim.x + threadIdx.x;
  if (e < NE) atomicAdd(&deg[ei[NE + e]], 1);
}

__global__ void k_scan(const int* __restrict__ deg, int* __restrict__ row_ptr,
                       int* __restrict__ cursor) {
  const int T = 1024;
  const int CH = (NN + T - 1) / T;
  __shared__ int ssum[T];
  int t = threadIdx.x;
  int base = t * CH;
  int s = 0;
  for (int i = 0; i < CH; i++) {
    int idx = base + i;
    if (idx < NN) s += deg[idx];
  }
  ssum[t] = s;
  __syncthreads();
  for (int off = 1; off < T; off <<= 1) {
    int v = (t >= off) ? ssum[t - off] : 0;
    __syncthreads();
    ssum[t] += v;
    __syncthreads();
  }
  int run = ssum[t] - s;
  for (int i = 0; i < CH; i++) {
    int idx = base + i;
    if (idx < NN) {
      row_ptr[idx] = run;
      cursor[idx] = run;
      run += deg[idx];
    }
  }
  if (t == 0) row_ptr[NN] = ssum[T - 1];
}

__global__ void k_scatter(const int* __restrict__ ei, int* __restrict__ cursor,
                          int* __restrict__ csr_src) {
  int e = blockIdx.x * blockDim.x + threadIdx.x;
  if (e < NE) {
    int d = ei[NE + e];
    int pos = atomicAdd(&cursor[d], 1);
    csr_src[pos] = ei[e];
  }
}

// ---------- weight transpose + bf16 convert: Wt[n][k] = W[k][n] ----------
__global__ void k_wt(const float* __restrict__ W, ushort* __restrict__ Wt, int K, int N) {
  __shared__ float tl[32][33];
  int bn = blockIdx.x * 32, bk = blockIdx.y * 32;
  int tx = threadIdx.x & 31, ty = threadIdx.x >> 5;
  for (int i = ty; i < 32; i += 8) tl[i][tx] = W[(size_t)(bk + i) * N + bn + tx];
  __syncthreads();
  for (int i = ty; i < 32; i += 8)
    Wt[(size_t)(bn + i) * K + bk + tx] = f2bf(tl[tx][i]);
}

// ---------- layer 1: collapsed attention vectors v_s/v_d[k][h] = sum_c W1[k,h*128+c]*a[h,c] ----------
__global__ void k_vsd(const float* __restrict__ W1, const float* __restrict__ as1,
                      const float* __restrict__ ad1, float* __restrict__ vs,
                      float* __restrict__ vd) {
  int t = threadIdx.x;  // 128, 88 active
  if (t >= 88) return;
  int side = t & 1, kh = t >> 1;  // kh = k*4+h
  int k = kh >> 2, h = kh & 3;
  const float* av = side ? ad1 : as1;
  float s = 0.f;
  for (int c = 0; c < HID; c++) s += W1[k * 512 + h * HID + c] * av[h * HID + c];
  (side ? vd : vs)[kh] = s;
}

// ---------- layer 1: per-node attention scores from raw x ----------
__global__ void k_ax(const float* __restrict__ x, const float* __restrict__ vs,
                     const float* __restrict__ vd, float* __restrict__ asrc,
                     float* __restrict__ adst) {
  int n = blockIdx.x * blockDim.x + threadIdx.x;
  if (n >= NN) return;
  float xr[F_IN];
#pragma unroll
  for (int k = 0; k < F_IN; k++) xr[k] = x[n * F_IN + k];
  float s[4] = {}, dd[4] = {};
#pragma unroll
  for (int k = 0; k < F_IN; k++)
#pragma unroll
    for (int h = 0; h < 4; h++) {
      s[h] += xr[k] * vs[k * 4 + h];
      dd[h] += xr[k] * vd[k * 4 + h];
    }
  *(f32x4*)(asrc + n * 4) = f32x4{s[0], s[1], s[2], s[3]};
  *(f32x4*)(adst + n * 4) = f32x4{dd[0], dd[1], dd[2], dd[3]};
}

// ---------- layer 1: aggregate RAW x (11-dim, L2-resident) -> P[n][4][11] f32 ----------
__global__ __launch_bounds__(256) void k_aggpre(
    const float* __restrict__ x, const float* __restrict__ asrc,
    const float* __restrict__ adst, const int* __restrict__ row_ptr,
    const int* __restrict__ csr_src, float* __restrict__ P) {
  const int CAP = 64;
  __shared__ int src_c[4][CAP];
  __shared__ float ea[4][CAP * 4];
  int t = threadIdx.x, lane = t & 63, wv = t >> 6;
  int d = blockIdx.x * 4 + wv;  // grid = NN/4 exact
  int start = row_ptr[d], deg = row_ptr[d + 1] - start;
  int dcap = min(deg, CAP);
  for (int i = lane; i < dcap; i += 64) src_c[wv][i] = csr_src[start + i];
  wave_fence();
  int hh = lane & 3;
  float adh = adst[d * 4 + hh];
  float m = MNEG, s = 0.f;
  int deg4 = deg * 4;
  for (int i = lane; i < deg4; i += 64) {
    int k = i >> 2;
    int sn = (k < CAP) ? src_c[wv][k] : csr_src[start + k];
    float v = lrelu(asrc[sn * 4 + hh] + adh);
    if (k < CAP) ea[wv][i] = v;
    float nm = fmaxf(m, v);
    s = s * __expf(m - nm) + __expf(v - nm);
    m = nm;
  }
#pragma unroll
  for (int off = 4; off < 64; off <<= 1) {
    float m2 = __shfl_xor(m, off);
    float s2 = __shfl_xor(s, off);
    float nm = fmaxf(m, m2);
    s = s * __expf(m - nm) + s2 * __expf(m2 - nm);
    m = nm;
  }
  float sinv = (s > 0.f) ? 1.f / s : 0.f;
  int dc4 = dcap * 4;
  for (int i = lane; i < dc4; i += 64) ea[wv][i] = __expf(ea[wv][i] - m) * sinv;
  wave_fence();
  // pass 2: lanes 0..43 own (h,k); others shadow h&3
  int hq = lane / F_IN;
  int k = lane - hq * F_IN;
  int h = hq & 3;
  float mh = __shfl(m, h), sih = __shfl(sinv, h);
  float adh2 = adst[d * 4 + h];
  float acc = 0.f;
  for (int e = 0; e < deg; e++) {
    int sn;
    float a;
    if (e < CAP) {
      sn = src_c[wv][e];
      a = ea[wv][e * 4 + h];
    } else {
      sn = csr_src[start + e];
      a = __expf(lrelu(asrc[sn * 4 + h] + adh2) - mh) * sih;
    }
    acc += a * x[sn * F_IN + k];
  }
  if (lane < 44) P[(size_t)d * 44 + lane] = acc;
}

// ---------- layer 1: out = elu(P @ W1 + b1), 16 nodes/block, W1 staged in LDS ----------
__global__ __launch_bounds__(256) void k_gemm_l1(
    const float* __restrict__ P, const float* __restrict__ W1,
    const float* __restrict__ b1, ushort* __restrict__ out) {
  __shared__ float sW[F_IN * 512];
  __shared__ float sP[16][44];
  int t = threadIdx.x;
  for (int i = t; i < F_IN * 512; i += 256) sW[i] = W1[i];
  int n0 = blockIdx.x * 16;
  for (int i = t; i < 16 * 44; i += 256)
    sP[i / 44][i % 44] = P[(size_t)(n0 + i / 44) * 44 + (i % 44)];
  __syncthreads();
  int j0 = 2 * t;
  int h = j0 >> 7;
  float b0 = b1[j0], bb = b1[j0 + 1];
  float w0[F_IN], w1v[F_IN];
#pragma unroll
  for (int k = 0; k < F_IN; k++) {
    w0[k] = sW[k * 512 + j0];
    w1v[k] = sW[k * 512 + j0 + 1];
  }
  for (int nn = 0; nn < 16; nn++) {
    float a0 = b0, a1 = bb;
#pragma unroll
    for (int k = 0; k < F_IN; k++) {
      float pv = sP[nn][h * F_IN + k];
      a0 += pv * w0[k];
      a1 += pv * w1v[k];
    }
    a0 = elu1(a0);
    a1 = elu1(a1);
    unsigned pk = (unsigned)f2bf(a0) | ((unsigned)f2bf(a1) << 16);
    *(unsigned*)(out + (size_t)(n0 + nn) * 512 + j0) = pk;
  }
}

// ---------- bf16 MFMA GEMM: C[M,N] = A[M,K] @ Bt[N,K]^T ----------
#define TM 128
#define TN 128
#define TK 64
__global__ __launch_bounds__(256) void k_mfma(const ushort* __restrict__ A,
                                              const ushort* __restrict__ Bt,
                                              ushort* __restrict__ C,
                                              int M, int N, int K) {
  __shared__ ushort lds[TM * TK + TN * TK];
  ushort* As = lds;
  ushort* Bs = lds + TM * TK;
  int tid = threadIdx.x;
  int lane = tid & 63, wv = tid >> 6;
  int wr = wv >> 1, wc = wv & 1;
  int bm0 = blockIdx.x * TM, bn0 = blockIdx.y * TN;
  int l15 = lane & 15, l4 = lane >> 4;
  f32x4 acc[4][4] = {};
  for (int k0 = 0; k0 < K; k0 += TK) {
#pragma unroll
    for (int it = 0; it < 4; ++it) {
      int chunk = it * 4 + wv;
      int pbase = chunk * 1024;
      int p = pbase + lane * 16;
      int prow = p >> 7;
      int lblk = ((p >> 4) & 7) ^ (prow & 7);
      int gr = bm0 + prow;
      gr = gr < M ? gr : M - 1;
      __builtin_amdgcn_global_load_lds(
          (const AS1 void*)(A + (size_t)gr * K + (k0 + lblk * 8)),
          (AS3 void*)((char*)As + pbase), 16, 0, 0);
      int gb = bn0 + prow;
      __builtin_amdgcn_global_load_lds(
          (const AS1 void*)(Bt + (size_t)gb * K + (k0 + lblk * 8)),
          (AS3 void*)((char*)Bs + pbase), 16, 0, 0);
    }
    __syncthreads();
#pragma unroll
    for (int kk = 0; kk < 2; ++kk) {
      int cb = kk * 4 + l4;
      short8 af[4], bfr[4];
#pragma unroll
      for (int m = 0; m < 4; ++m) {
        int row = wr * 64 + m * 16 + l15;
        af[m] = *(const short8*)((const char*)As + row * 128 + ((cb ^ (row & 7)) << 4));
      }
#pragma unroll
      for (int n = 0; n < 4; ++n) {
        int row = wc * 64 + n * 16 + l15;
        bfr[n] = *(const short8*)((const char*)Bs + row * 128 + ((cb ^ (row & 7)) << 4));
      }
#pragma unroll
      for (int m = 0; m < 4; ++m)
#pragma unroll
        for (int n = 0; n < 4; ++n)
          acc[m][n] = __builtin_amdgcn_mfma_f32_16x16x32_bf16(af[m], bfr[n], acc[m][n], 0, 0, 0);
    }
    __syncthreads();
  }
#pragma unroll
  for (int m = 0; m < 4; ++m) {
#pragma unroll
    for (int r = 0; r < 4; ++r) {
      int row = bm0 + wr * 64 + m * 16 + l4 * 4 + r;
      if (row < M) {
#pragma unroll
        for (int n = 0; n < 4; ++n) {
          int col = bn0 + wc * 64 + n * 16 + l15;
          C[(size_t)row * N + col] = f2bf(acc[m][n][r]);
        }
      }
    }
  }
}

// ---------- attention coefficients from transformed features (layers 2,3) ----------
template <int H>
__global__ void k_alpha(const ushort* __restrict__ h, const float* __restrict__ a_src,
                        const float* __restrict__ a_dst, float* __restrict__ asrc,
                        float* __restrict__ adst) {
  int t = threadIdx.x;  // 256
  int lane = t & 63;
  int n_g, h_g;
  if (H == 4) {
    n_g = blockIdx.x * 4 + (t >> 6);
    h_g = lane >> 4;
  } else {
    n_g = blockIdx.x * 16 + (t >> 4);
    h_g = 0;
  }
  if (n_g >= NN) return;
  int cl = lane & 15;
  short8 hv = *(const short8*)(h + (size_t)n_g * (H * 128) + h_g * 128 + cl * 8);
  const float* as = a_src + h_g * 128 + cl * 8;
  const float* ad = a_dst + h_g * 128 + cl * 8;
  float s1 = 0.f, s2 = 0.f;
#pragma unroll
  for (int j = 0; j < 8; j++) {
    float v = bf2f((ushort)hv[j]);
    s1 += v * as[j];
    s2 += v * ad[j];
  }
#pragma unroll
  for (int off = 1; off < 16; off <<= 1) {
    s1 += __shfl_xor(s1, off);
    s2 += __shfl_xor(s2, off);
  }
  if (cl == 0) {
    asrc[n_g * H + h_g] = s1;
    adst[n_g * H + h_g] = s2;
  }
}

// ---------- layer-2 aggregate: wave-per-node, H=4, no barriers ----------
__global__ __launch_bounds__(256) void k_agg4w(
    const ushort* __restrict__ h, const float* __restrict__ asrc,
    const float* __restrict__ adst, const int* __restrict__ row_ptr,
    const int* __restrict__ csr_src, const float* __restrict__ bias,
    ushort* __restrict__ out) {
  const int CAP = 64;
  __shared__ int src_c[4][CAP];
  __shared__ float ea[4][CAP * 4];
  int t = threadIdx.x, lane = t & 63, wv = t >> 6;
  int d = blockIdx.x * 4 + wv;  // grid = NN/4 exact
  int start = row_ptr[d], deg = row_ptr[d + 1] - start;
  int dcap = min(deg, CAP);
  for (int i = lane; i < dcap; i += 64) src_c[wv][i] = csr_src[start + i];
  wave_fence();
  int hh = lane & 3;
  float adh = adst[d * 4 + hh];
  float m = MNEG, s = 0.f;
  int deg4 = deg * 4;
  for (int i = lane; i < deg4; i += 64) {
    int k = i >> 2;
    int sn = (k < CAP) ? src_c[wv][k] : csr_src[start + k];
    float v = lrelu(asrc[sn * 4 + hh] + adh);
    if (k < CAP) ea[wv][i] = v;
    float nm = fmaxf(m, v);
    s = s * __expf(m - nm) + __expf(v - nm);
    m = nm;
  }
#pragma unroll
  for (int off = 4; off < 64; off <<= 1) {
    float m2 = __shfl_xor(m, off);
    float s2 = __shfl_xor(s, off);
    float nm = fmaxf(m, m2);
    s = s * __expf(m - nm) + s2 * __expf(m2 - nm);
    m = nm;
  }
  float sinv = (s > 0.f) ? 1.f / s : 0.f;
  int dc4 = dcap * 4;
  for (int i = lane; i < dc4; i += 64) ea[wv][i] = __expf(ea[wv][i] - m) * sinv;
  wave_fence();
  // gather pass: lane covers cols lane*8..+7, head hl = lane>>4
  int hl = lane >> 4;
  float mh = __shfl(m, hl), sih = __shfl(sinv, hl);
  float adh2 = adst[d * 4 + hl];
  float acc[8] = {};
  for (int k = 0; k < deg; k++) {
    int sn;
    float a;
    if (k < CAP) {
      sn = src_c[wv][k];
      a = ea[wv][k * 4 + hl];
    } else {
      sn = csr_src[start + k];
      a = __expf(lrelu(asrc[sn * 4 + hl] + adh2) - mh) * sih;
    }
    short8 hv = *(const short8*)(h + (size_t)sn * 512 + lane * 8);
#pragma unroll
    for (int j = 0; j < 8; j++) acc[j] += a * bf2f((ushort)hv[j]);
  }
  const float* bp = bias + lane * 8;
  unsigned pk[4];
#pragma unroll
  for (int j = 0; j < 4; j++) {
    float o0 = elu1(acc[2 * j] + bp[2 * j]);
    float o1 = elu1(acc[2 * j + 1] + bp[2 * j + 1]);
    pk[j] = (unsigned)f2bf(o0) | ((unsigned)f2bf(o1) << 16);
  }
  *(uint4*)(out + (size_t)d * 512 + lane * 8) = make_uint4(pk[0], pk[1], pk[2], pk[3]);
}

// ---------- layer-3 aggregate: wave-per-node, H=1, no barriers, no ELU ----------
__global__ __launch_bounds__(256) void k_agg1w(
    const ushort* __restrict__ h, const float* __restrict__ asrc,
    const float* __restrict__ adst, const int* __restrict__ row_ptr,
    const int* __restrict__ csr_src, const float* __restrict__ bias,
    ushort* __restrict__ out) {
  const int CAP = 64;
  __shared__ int src_c[4][CAP];
  __shared__ float ea[4][CAP];
  int t = threadIdx.x, lane = t & 63, wv = t >> 6;
  int d = blockIdx.x * 4 + wv;
  int start = row_ptr[d], deg = row_ptr[d + 1] - start;
  int dcap = min(deg, CAP);
  for (int i = lane; i < dcap; i += 64) src_c[wv][i] = csr_src[start + i];
  wave_fence();
  float adh = adst[d];
  float m = MNEG, s = 0.f;
  for (int i = lane; i < deg; i += 64) {
    int sn = (i < CAP) ? src_c[wv][i] : csr_src[start + i];
    float v = lrelu(asrc[sn] + adh);
    if (i < CAP) ea[wv][i] = v;
    float nm = fmaxf(m, v);
    s = s * __expf(m - nm) + __expf(v - nm);
    m = nm;
  }
#pragma unroll
  for (int off = 1; off < 64; off <<= 1) {
    float m2 = __shfl_xor(m, off);
    float s2 = __shfl_xor(s, off);
    float nm = fmaxf(m, m2);
    s = s * __expf(m - nm) + s2 * __expf(m2 - nm);
    m = nm;
  }
  float sinv = (s > 0.f) ? 1.f / s : 0.f;
  for (int i = lane; i < dcap; i += 64) ea[wv][i] = __expf(ea[wv][i] - m) * sinv;
  wave_fence();
  float acc0 = 0.f, acc1 = 0.f;
  for (int k = 0; k < deg; k++) {
    int sn;
    float a;
    if (k < CAP) {
      sn = src_c[wv][k];
      a = ea[wv][k];
    } else {
      sn = csr_src[start + k];
      a = __expf(lrelu(asrc[sn] + adh) - m) * sinv;
    }
    unsigned hv = *(const unsigned*)(h + (size_t)sn * 128 + lane * 2);
    acc0 += a * bf2f((ushort)(hv & 0xffff));
    acc1 += a * bf2f((ushort)(hv >> 16));
  }
  float o0 = acc0 + bias[lane * 2];
  float o1 = acc1 + bias[lane * 2 + 1];
  unsigned pk = (unsigned)f2bf(o0) | ((unsigned)f2bf(o1) << 16);
  *(unsigned*)(out + (size_t)d * 128 + lane * 2) = pk;
}

// ---------- graph mean + heads ----------
__global__ __launch_bounds__(256) void k_colsum(const ushort* __restrict__ h3,
                                                float* __restrict__ gsum) {
  __shared__ float partial[16 * 128];
  int t = threadIdx.x;
  int rg = t >> 4, cl = t & 15;
  int nb = gridDim.x;
  int per = (NN + nb - 1) / nb;
  int r0 = blockIdx.x * per, r1 = min(NN, r0 + per);
  float acc[8] = {};
  for (int r = r0 + rg; r < r1; r += 16) {
    short8 hv = *(const short8*)(h3 + (size_t)r * 128 + cl * 8);
#pragma unroll
    for (int j = 0; j < 8; j++) acc[j] += bf2f((ushort)hv[j]);
  }
#pragma unroll
  for (int j = 0; j < 8; j++) partial[rg * 128 + cl * 8 + j] = acc[j];
  __syncthreads();
  if (t < 128) {
    float s = 0.f;
    for (int q = 0; q < 16; q++) s += partial[q * 128 + t];
    atomicAdd(&gsum[t], s);
  }
}

__global__ void k_head(const float* __restrict__ gsum, const ushort* __restrict__ h3,
                       const int* __restrict__ curp, const float* __restrict__ pw1,
                       const float* __restrict__ pb1, const float* __restrict__ pw2,
                       const float* __restrict__ pb2, const float* __restrict__ vw1,
                       const float* __restrict__ vb1, const float* __restrict__ vw2,
                       const float* __restrict__ vb2, float* __restrict__ outp) {
  __shared__ float comb[HID], ph[HID], vh[HID];
  int t = threadIdx.x;  // 128
  int cur = curp[0];
  comb[t] = gsum[t] * (1.f / NN) + bf2f(h3[(size_t)cur * HID + t]);
  __syncthreads();
  float accp = pb1[t], accv = vb1[t];
  for (int k = 0; k < HID; k++) {
    float cv = comb[k];
    accp += cv * pw1[k * HID + t];
    accv += cv * vw1[k * HID + t];
  }
  ph[t] = fmaxf(accp, 0.f);
  vh[t] = fmaxf(accv, 0.f);
  __syncthreads();
  if (t < 6) {
    float a = pb2[t];
    for (int k = 0; k < HID; k++) a += ph[k] * pw2[k * 6 + t];
    outp[t] = a;
  }
  if (t == 6) {
    float a = vb2[0];
    for (int k = 0; k < HID; k++) a += vh[k] * vw2[k];
    outp[6] = a;
  }
}

extern "C" void kernel_launch(void* const* d_in, const int* in_sizes, int n_in,
                              void* d_out, int out_size, void* d_ws, size_t ws_size,
                              hipStream_t stream) {
  const float* x = (const float*)d_in[0];
  const int* ei = (const int*)d_in[1];
  const int* cur = (const int*)d_in[2];
  const float* W1 = (const float*)d_in[3];
  const float* as1 = (const float*)d_in[4];
  const float* ad1 = (const float*)d_in[5];
  const float* b1 = (const float*)d_in[6];
  const float* W2 = (const float*)d_in[7];
  const float* as2 = (const float*)d_in[8];
  const float* ad2 = (const float*)d_in[9];
  const float* b2 = (const float*)d_in[10];
  const float* W3 = (const float*)d_in[11];
  const float* as3 = (const float*)d_in[12];
  const float* ad3 = (const float*)d_in[13];
  const float* b3 = (const float*)d_in[14];
  const float* pw1 = (const float*)d_in[15];
  const float* pb1 = (const float*)d_in[16];
  const float* pw2 = (const float*)d_in[17];
  const float* pb2 = (const float*)d_in[18];
  const float* vw1 = (const float*)d_in[19];
  const float* vb1 = (const float*)d_in[20];
  const float* vw2 = (const float*)d_in[21];
  const float* vb2 = (const float*)d_in[22];
  float* out = (float*)d_out;

  char* w = (char*)d_ws;
  ushort* G = (ushort*)w;    w += (size_t)NN * 512 * 2;
  ushort* Abuf = (ushort*)w; w += (size_t)NN * 512 * 2;
  ushort* Wt2 = (ushort*)w;  w += (size_t)512 * 512 * 2;
  ushort* Wt3 = (ushort*)w;  w += (size_t)128 * 512 * 2;
  float* P = (float*)w;      w += (size_t)NN * 44 * 4;
  float* asrc = (float*)w;   w += (size_t)NN * 4 * 4;
  float* adst = (float*)w;   w += (size_t)NN * 4 * 4;
  int* deg = (int*)w;        w += (size_t)NN * 4;
  int* cursor = (int*)w;     w += (size_t)NN * 4;
  int* row_ptr = (int*)w;    w += (size_t)(NN + 1) * 4;
  int* csr_src = (int*)w;    w += (size_t)NE * 4;
  float* gsum = (float*)w;   w += (size_t)HID * 4;
  float* vs = (float*)w;     w += 44 * 4;
  float* vd = (float*)w;     w += 44 * 4;

  hipMemsetAsync(deg, 0, NN * 4, stream);
  hipMemsetAsync(gsum, 0, HID * 4, stream);

  k_deg<<<(NE + 255) / 256, 256, 0, stream>>>(ei, deg);
  k_scan<<<1, 1024, 0, stream>>>(deg, row_ptr, cursor);
  k_scatter<<<(NE + 255) / 256, 256, 0, stream>>>(ei, cursor, csr_src);

  k_wt<<<dim3(512 / 32, 512 / 32), 256, 0, stream>>>(W2, Wt2, 512, 512);
  k_wt<<<dim3(128 / 32, 512 / 32), 256, 0, stream>>>(W3, Wt3, 512, 128);

  const int GB = (NN + TM - 1) / TM;  // 391

  // Layer 1 (pre-aggregation trick: aggregate raw x, then GEMM)
  k_vsd<<<1, 128, 0, stream>>>(W1, as1, ad1, vs, vd);
  k_ax<<<(NN + 255) / 256, 256, 0, stream>>>(x, vs, vd, asrc, adst);
  k_aggpre<<<NN / 4, 256, 0, stream>>>(x, asrc, adst, row_ptr, csr_src, P);
  k_gemm_l1<<<NN / 16, 256, 0, stream>>>(P, W1, b1, Abuf);

  // Layer 2: 512 -> 4x128 (bf16 MFMA) + wave-per-node aggregate
  k_mfma<<<dim3(GB, 4), 256, 0, stream>>>(Abuf, Wt2, G, NN, 512, 512);
  k_alpha<4><<<(NN + 3) / 4, 256, 0, stream>>>(G, as2, ad2, asrc, adst);
  k_agg4w<<<NN / 4, 256, 0, stream>>>(G, asrc, adst, row_ptr, csr_src, b2, Abuf);

  // Layer 3: 512 -> 128 (bf16 MFMA) + wave-per-node aggregate
  k_mfma<<<dim3(GB, 1), 256, 0, stream>>>(Abuf, Wt3, G, NN, 128, 512);
  k_alpha<1><<<(NN + 15) / 16, 256, 0, stream>>>(G, as3, ad3, asrc, adst);
  k_agg1w<<<NN / 4, 256, 0, stream>>>(G, asrc, adst, row_ptr, csr_src, b3, Abuf);

  // Heads
  k_colsum<<<256, 256, 0, stream>>>(Abuf, gsum);
  k_head<<<1, 128, 0, stream>>>(gsum, Abuf, cur, pw1, pb1, pw2, pb2, vw1, vb1, vw2, vb2, out);
}